// Round 4
// baseline (246.885 us; speedup 1.0000x reference)
//
#include <hip/hip_runtime.h>
#include <cstdint>
#include <cstddef>

#define S_LEN 4096
#define HID   512
#define NHEAD 8
#define HD    64
// (1/sqrt(64)) * log2(e)
#define SCALE_LOG2E 0.1803368801111204f

typedef __bf16 bf16;
typedef __bf16 bf16x8 __attribute__((ext_vector_type(8)));
typedef __bf16 bf16x4 __attribute__((ext_vector_type(4)));
typedef float  f32x4  __attribute__((ext_vector_type(4)));

// ---------------- fp32 -> bf16 conversion ----------------
__global__ __launch_bounds__(256) void cvt_f32_bf16(const float* __restrict__ src,
                                                    bf16* __restrict__ dst, int n) {
    int i = (blockIdx.x * 256 + threadIdx.x) * 4;
    if (i + 3 < n) {
        const float4 v = *(const float4*)(src + i);
        bf16x4 o;
        o[0] = (bf16)v.x; o[1] = (bf16)v.y; o[2] = (bf16)v.z; o[3] = (bf16)v.w;
        *(bf16x4*)(dst + i) = o;
    }
}

// 4 weight matrices (512x512 each) in one launch: blockIdx.y selects which.
__global__ __launch_bounds__(256) void cvt_w4(
    const float* __restrict__ s0, const float* __restrict__ s1,
    const float* __restrict__ s2, const float* __restrict__ s3,
    bf16* __restrict__ d0, bf16* __restrict__ d1,
    bf16* __restrict__ d2, bf16* __restrict__ d3) {
    const float* src; bf16* dst;
    switch (blockIdx.y) {
        case 0: src = s0; dst = d0; break;
        case 1: src = s1; dst = d1; break;
        case 2: src = s2; dst = d2; break;
        default: src = s3; dst = d3; break;
    }
    int i = (blockIdx.x * 256 + threadIdx.x) * 4;
    const float4 v = *(const float4*)(src + i);
    bf16x4 o;
    o[0] = (bf16)v.x; o[1] = (bf16)v.y; o[2] = (bf16)v.z; o[3] = (bf16)v.w;
    *(bf16x4*)(dst + i) = o;
}

// ---------------- GEMM: Y[m][n] = sum_k X[m][k] * W[n][k] ----------------
#define BM 128
#define BN 128
#define BKK 64

template<int OUTF32>
__global__ __launch_bounds__(256) void gemm_bt(
    const bf16* __restrict__ X,
    const bf16* __restrict__ W0, const bf16* __restrict__ W1, const bf16* __restrict__ W2,
    void* __restrict__ Y0, int M, int N, int K)
{
    const bf16* W = (blockIdx.z == 0) ? W0 : (blockIdx.z == 1 ? W1 : W2);
    const int m0 = blockIdx.y * BM, n0 = blockIdx.x * BN;
    __shared__ bf16 lA[BM][8][8];
    __shared__ bf16 lB[BN][8][8];
    const int tid = threadIdx.x;
    const int lane = tid & 63, w = tid >> 6;
    const int l16 = lane & 15, lc = lane >> 4, l7 = lane & 7;
    const int wm = (w & 1) * 64, wn = (w >> 1) * 64;
    f32x4 acc[4][4] = {};

    for (int k0 = 0; k0 < K; k0 += BKK) {
        __syncthreads();
#pragma unroll
        for (int i = 0; i < 4; i++) {
            int uu = tid + 256 * i;
            int m = uu >> 3, c = uu & 7;
            *(float4*)(&lA[m][c ^ (m & 7)][0]) =
                *(const float4*)(X + (size_t)(m0 + m) * K + k0 + 8 * c);
            *(float4*)(&lB[m][c ^ (m & 7)][0]) =
                *(const float4*)(W + (size_t)(n0 + m) * K + k0 + 8 * c);
        }
        __syncthreads();
#pragma unroll
        for (int ks = 0; ks < 2; ks++) {
            bf16x8 af[4], bfr[4];
#pragma unroll
            for (int i = 0; i < 4; i++) {
                af[i]  = *(const bf16x8*)(&lA[wm + 16 * i + l16][(4 * ks + lc) ^ l7][0]);
                bfr[i] = *(const bf16x8*)(&lB[wn + 16 * i + l16][(4 * ks + lc) ^ l7][0]);
            }
#pragma unroll
            for (int i = 0; i < 4; i++)
#pragma unroll
                for (int j = 0; j < 4; j++)
                    acc[i][j] = __builtin_amdgcn_mfma_f32_16x16x32_bf16(
                        af[i], bfr[j], acc[i][j], 0, 0, 0);
        }
    }
    if (OUTF32) {
        float* Y = (float*)Y0;
#pragma unroll
        for (int i = 0; i < 4; i++) {
            int row = m0 + wm + 16 * i + 4 * lc;
#pragma unroll
            for (int j = 0; j < 4; j++) {
                int col = n0 + wn + 16 * j + l16;
#pragma unroll
                for (int r = 0; r < 4; r++)
                    Y[(size_t)(row + r) * N + col] = acc[i][j][r];
            }
        }
    } else {
        bf16* Y = (bf16*)Y0 + (size_t)blockIdx.z * M * N;
#pragma unroll
        for (int i = 0; i < 4; i++) {
            int row = m0 + wm + 16 * i + 4 * lc;
#pragma unroll
            for (int j = 0; j < 4; j++) {
                int col = n0 + wn + 16 * j + l16;
#pragma unroll
                for (int r = 0; r < 4; r++)
                    Y[(size_t)(row + r) * N + col] = (bf16)acc[i][j][r];
            }
        }
    }
}

// ---------------- RoPE + reshape to per-head [h][s][64] ----------------
__global__ __launch_bounds__(256) void rope_qk(
    const bf16* __restrict__ QKV, const float* __restrict__ cosT,
    const float* __restrict__ sinT, const int* __restrict__ nregp,
    bf16* __restrict__ Qh, bf16* __restrict__ Kh)
{
    const int s = blockIdx.x, t = threadIdx.x;
    const int h = t >> 5, d = t & 31;
    const int nreg = *nregp;
    float c = 1.f, sn = 0.f;
    if (s >= nreg) {
        const int p = s - nreg;
        c  = cosT[p * HD + d];
        sn = sinT[p * HD + d];
    }
    {
        const bf16* Q = QKV;
        float q0 = (float)Q[(size_t)s * HID + h * HD + d];
        float q1 = (float)Q[(size_t)s * HID + h * HD + d + 32];
        bf16* outp = Qh + ((size_t)h * S_LEN + s) * HD;
        outp[d]      = (bf16)(q0 * c - q1 * sn);
        outp[d + 32] = (bf16)(q1 * c + q0 * sn);
    }
    {
        const bf16* Kk = QKV + (size_t)S_LEN * HID;
        float k0v = (float)Kk[(size_t)s * HID + h * HD + d];
        float k1v = (float)Kk[(size_t)s * HID + h * HD + d + 32];
        bf16* outp = Kh + ((size_t)h * S_LEN + s) * HD;
        outp[d]      = (bf16)(k0v * c - k1v * sn);
        outp[d + 32] = (bf16)(k1v * c + k0v * sn);
    }
}

// ---------------- V transpose: [s][h*64+d] -> Vt[h][d][s] ----------------
__global__ __launch_bounds__(256) void v_trans(const bf16* __restrict__ QKV,
                                               bf16* __restrict__ Vt)
{
    const int s0 = blockIdx.x * 64, h = blockIdx.y;
    const bf16* V = QKV + (size_t)2 * S_LEN * HID;
    __shared__ bf16 tile[64][72];
    const int t = threadIdx.x;
#pragma unroll
    for (int i = 0; i < 2; i++) {
        int uu = t + 256 * i;
        int r = uu >> 3, cc = (uu & 7) * 8;
        *(float4*)(&tile[r][cc]) =
            *(const float4*)(V + (size_t)(s0 + r) * HID + h * HD + cc);
    }
    __syncthreads();
#pragma unroll
    for (int i = 0; i < 2; i++) {
        int uu = t + 256 * i;
        int d = uu >> 3, sc = (uu & 7) * 8;
        bf16x8 o;
#pragma unroll
        for (int j = 0; j < 8; j++) o[j] = tile[sc + j][d];
        *(bf16x8*)(Vt + ((size_t)h * HD + d) * S_LEN + s0 + sc) = o;
    }
}

// ---------------- Causal attention, S^T form, key-split two-pass ----------------
// One wave per block, 16 q-rows, HALF the key range per block (grid z=2).
// No-max softmax (scores bounded) => partials combine by pure addition:
// each chunk writes unnormalized O^T partial (fp32) + l partial; attn_combine
// sums, divides, converts. __launch_bounds__(64,2): 256-VGPR budget so
// kf/kn/vf all stay in flight (round-3 VGPR=76 serialized the loads:
// ~16 x ~300cy L2 roundtrips = 5060 cy/iter measured).
__global__ __launch_bounds__(64, 2) void attn_part(
    const bf16* __restrict__ Qh, const bf16* __restrict__ Kh,
    const bf16* __restrict__ Vt, float* __restrict__ Opart,
    float* __restrict__ Lpart)
{
    const int h = blockIdx.x;
    const int rt = 255 - (int)blockIdx.y;    // longest-first (LPT)
    const int half = blockIdx.z;
    const int qb = rt * 16;
    const int nkt = (rt >> 2) + 1;
    const int kmid = nkt >> 1;               // chunk0: [0,kmid)  chunk1: [kmid,nkt)
    const int k0 = half ? kmid : 0;
    const int k1 = half ? nkt : kmid;
    const int lane = threadIdx.x;
    const int l16 = lane & 15, lc = lane >> 4;

    float* Op = Opart + ((size_t)(h * 256 + rt) * 2 + half) * 1024;
    float* Lp = Lpart + ((size_t)(h * 256 + rt) * 2 + half) * 16;

    if (k0 >= k1) {                          // empty chunk (rt=0, half=0): zeros
        const f32x4 z = {0.f, 0.f, 0.f, 0.f};
#pragma unroll
        for (int i = 0; i < 4; i++)
            *(f32x4*)(Op + 4 * (lane + 64 * i)) = z;
        if (lane < 16) Lp[lane] = 0.f;
        return;
    }

    __shared__ bf16 lPT[16][76];             // P^T [q][key], pad 76
    const bf16* Qb_ = Qh + (size_t)h * S_LEN * HD;
    const bf16* Kp  = Kh + (size_t)h * S_LEN * HD + (size_t)l16 * HD + lc * 8;
    const bf16* Vp  = Vt + (size_t)h * HD * S_LEN + (size_t)l16 * S_LEN + lc * 8;

    bf16x8 qf[2];
    {
        const bf16* qrow = Qb_ + (size_t)(qb + l16) * HD;
        qf[0] = *(const bf16x8*)(qrow + lc * 8);
        qf[1] = *(const bf16x8*)(qrow + 32 + lc * 8);
    }
    f32x4 oacc[4] = {};
    float l_sum = 0.f;

    bf16x8 kf[2][4];
#pragma unroll
    for (int ks = 0; ks < 2; ks++)
#pragma unroll
        for (int j = 0; j < 4; j++)
            kf[ks][j] = *(const bf16x8*)(Kp + (size_t)(k0 * 64 + j * 16) * HD + ks * 32);

    for (int kt = k0; kt < k1; kt++) {
        // V tile loads (consumed after softmax)
        bf16x8 vf[2][4];
#pragma unroll
        for (int ks = 0; ks < 2; ks++)
#pragma unroll
            for (int j = 0; j < 4; j++)
                vf[ks][j] = *(const bf16x8*)(Vp + (size_t)j * 16 * S_LEN +
                                             kt * 64 + ks * 32);

        // S^T = K Q^T : sacc[j] rows = keys 16j+4lc+r, col = q = l16
        f32x4 sacc[4] = {};
#pragma unroll
        for (int ks = 0; ks < 2; ks++)
#pragma unroll
            for (int j = 0; j < 4; j++)
                sacc[j] = __builtin_amdgcn_mfma_f32_16x16x32_bf16(
                    kf[ks][j], qf[ks], sacc[j], 0, 0, 0);

        // prefetch next K tile during softmax
        bf16x8 kn[2][4];
        if (kt + 1 < k1) {
#pragma unroll
            for (int ks = 0; ks < 2; ks++)
#pragma unroll
                for (int j = 0; j < 4; j++)
                    kn[ks][j] = *(const bf16x8*)(Kp + (size_t)((kt + 1) * 64 + j * 16) * HD +
                                                 ks * 32);
        }

        // p = exp2(s*scale); mask key>q on the diagonal tile (always in chunk1)
        float pv[4][4];
#pragma unroll
        for (int j = 0; j < 4; j++)
#pragma unroll
            for (int r = 0; r < 4; r++)
                pv[j][r] = __builtin_amdgcn_exp2f(sacc[j][r] * SCALE_LOG2E);
        if (kt == nkt - 1) {
            const int qg = qb + l16;
#pragma unroll
            for (int j = 0; j < 4; j++)
#pragma unroll
                for (int r = 0; r < 4; r++) {
                    const int keyg = kt * 64 + 16 * j + 4 * lc + r;
                    if (keyg > qg) pv[j][r] = 0.f;
                }
        }
#pragma unroll
        for (int j = 0; j < 4; j++)
            l_sum += (pv[j][0] + pv[j][1]) + (pv[j][2] + pv[j][3]);

        // P^T -> LDS [q][key], no barrier (single wave)
#pragma unroll
        for (int j = 0; j < 4; j++) {
            bf16x4 pp;
#pragma unroll
            for (int r = 0; r < 4; r++) pp[r] = (bf16)pv[j][r];
            *(bf16x4*)(&lPT[l16][16 * j + 4 * lc]) = pp;
        }

        bf16x8 pb[2];
#pragma unroll
        for (int ks = 0; ks < 2; ks++)
            pb[ks] = *(const bf16x8*)(&lPT[l16][32 * ks + 8 * lc]);

        // O^T += V^T P^T
#pragma unroll
        for (int ks = 0; ks < 2; ks++)
#pragma unroll
            for (int j = 0; j < 4; j++)
                oacc[j] = __builtin_amdgcn_mfma_f32_16x16x32_bf16(
                    vf[ks][j], pb[ks], oacc[j], 0, 0, 0);

#pragma unroll
        for (int ks = 0; ks < 2; ks++)
#pragma unroll
            for (int j = 0; j < 4; j++)
                kf[ks][j] = kn[ks][j];
    }

    // l: combine the 4 lc-replicas of each q
    l_sum += __shfl_xor(l_sum, 16, 64);
    l_sum += __shfl_xor(l_sum, 32, 64);
    if (lane < 16) Lp[lane] = l_sum;

    // store unnormalized O^T partial: Op[q*64+d], lane holds d=16j+4lc+r, q=l16
#pragma unroll
    for (int j = 0; j < 4; j++)
        *(f32x4*)(Op + (size_t)l16 * 64 + 16 * j + 4 * lc) = oacc[j];
}

// combine: O = (O0+O1)/(l0+l1), convert to bf16 [s][h*64+d]
__global__ __launch_bounds__(256) void attn_combine(
    const float* __restrict__ Opart, const float* __restrict__ Lpart,
    bf16* __restrict__ Ob)
{
    const int h = blockIdx.x, rt = blockIdx.y;
    const size_t base = (size_t)(h * 256 + rt) * 2;
    const float* O0 = Opart + base * 1024;
    const float* O1 = O0 + 1024;
    const int t = threadIdx.x;
    const int q = t >> 4, dc = (t & 15) * 4;
    const float l = Lpart[base * 16 + q] + Lpart[base * 16 + 16 + q];
    const float inv = 1.0f / l;
    f32x4 a = *(const f32x4*)(O0 + q * 64 + dc);
    f32x4 b = *(const f32x4*)(O1 + q * 64 + dc);
    bf16x4 o;
#pragma unroll
    for (int r = 0; r < 4; r++) o[r] = (bf16)((a[r] + b[r]) * inv);
    *(bf16x4*)(Ob + (size_t)(rt * 16 + q) * HID + h * HD + dc) = o;
}

// ---------------- launch ----------------
extern "C" void kernel_launch(void* const* d_in, const int* in_sizes, int n_in,
                              void* d_out, int out_size, void* d_ws, size_t ws_size,
                              hipStream_t stream) {
    const float* hs   = (const float*)d_in[0];
    const float* Wq   = (const float*)d_in[1];
    const float* Wk   = (const float*)d_in[2];
    const float* Wv   = (const float*)d_in[3];
    const float* Wo   = (const float*)d_in[4];
    const float* cosT = (const float*)d_in[5];
    const float* sinT = (const float*)d_in[6];
    const int*   nreg = (const int*)d_in[7];

    char* ws = (char*)d_ws;
    const size_t MiB = 1 << 20;
    bf16*  Xb    = (bf16*)(ws);                         // 0-4 MiB
    bf16*  Wqb   = (bf16*)(ws + 4 * MiB);               // 4-6 MiB: weights
    bf16*  Wkb   = (bf16*)(ws + 4 * MiB + 512 * 1024);
    bf16*  Wvb   = (bf16*)(ws + 5 * MiB);
    bf16*  Wob   = (bf16*)(ws + 5 * MiB + 512 * 1024);
    bf16*  QKVf  = (bf16*)(ws + 6 * MiB);               // 6-18 MiB (dead after v_trans)
    float* Opart = (float*)(ws + 6 * MiB);              // 6-22 MiB (reuses QKVf region)
    bf16*  Qh    = (bf16*)(ws + 22 * MiB);              // 22-26
    bf16*  Kh    = (bf16*)(ws + 26 * MiB);              // 26-30
    bf16*  Vt    = (bf16*)(ws + 30 * MiB);              // 30-34
    bf16*  Ob    = (bf16*)(ws + 34 * MiB);              // 34-38
    float* Lpart = (float*)(ws + 38 * MiB);             // 38-38.25

    cvt_f32_bf16<<<2048, 256, 0, stream>>>(hs, Xb, S_LEN * HID);
    cvt_w4<<<dim3(256, 4), 256, 0, stream>>>(Wq, Wk, Wv, Wo, Wqb, Wkb, Wvb, Wob);

    gemm_bt<0><<<dim3(4, 32, 3), 256, 0, stream>>>(Xb, Wqb, Wkb, Wvb,
                                                   (void*)QKVf, S_LEN, HID, HID);
    rope_qk<<<4096, 256, 0, stream>>>(QKVf, cosT, sinT, nreg, Qh, Kh);
    v_trans<<<dim3(64, 8), 256, 0, stream>>>(QKVf, Vt);
    attn_part<<<dim3(8, 256, 2), 64, 0, stream>>>(Qh, Kh, Vt, Opart, Lpart);
    attn_combine<<<dim3(8, 256), 256, 0, stream>>>(Opart, Lpart, Ob);
    gemm_bt<1><<<dim3(4, 32, 1), 256, 0, stream>>>(Ob, Wob, Wob, Wob,
                                                   d_out, S_LEN, HID, HID);
}

// Round 5
// 171.246 us; speedup vs baseline: 1.4417x; 1.4417x over previous
//
#include <hip/hip_runtime.h>
#include <cstdint>
#include <cstddef>

#define S_LEN 4096
#define HID   512
#define NHEAD 8
#define HD    64
// (1/sqrt(64)) * log2(e)
#define SCALE_LOG2E 0.1803368801111204f

typedef __bf16 bf16;
typedef __bf16 bf16x8 __attribute__((ext_vector_type(8)));
typedef __bf16 bf16x4 __attribute__((ext_vector_type(4)));
typedef float  f32x4  __attribute__((ext_vector_type(4)));

// ---------------- fp32 -> bf16 conversion ----------------
__global__ __launch_bounds__(256) void cvt_f32_bf16(const float* __restrict__ src,
                                                    bf16* __restrict__ dst, int n) {
    int i = (blockIdx.x * 256 + threadIdx.x) * 4;
    if (i + 3 < n) {
        const float4 v = *(const float4*)(src + i);
        bf16x4 o;
        o[0] = (bf16)v.x; o[1] = (bf16)v.y; o[2] = (bf16)v.z; o[3] = (bf16)v.w;
        *(bf16x4*)(dst + i) = o;
    }
}

// 4 weight matrices (512x512 each) in one launch: blockIdx.y selects which.
__global__ __launch_bounds__(256) void cvt_w4(
    const float* __restrict__ s0, const float* __restrict__ s1,
    const float* __restrict__ s2, const float* __restrict__ s3,
    bf16* __restrict__ d0, bf16* __restrict__ d1,
    bf16* __restrict__ d2, bf16* __restrict__ d3) {
    const float* src; bf16* dst;
    switch (blockIdx.y) {
        case 0: src = s0; dst = d0; break;
        case 1: src = s1; dst = d1; break;
        case 2: src = s2; dst = d2; break;
        default: src = s3; dst = d3; break;
    }
    int i = (blockIdx.x * 256 + threadIdx.x) * 4;
    const float4 v = *(const float4*)(src + i);
    bf16x4 o;
    o[0] = (bf16)v.x; o[1] = (bf16)v.y; o[2] = (bf16)v.z; o[3] = (bf16)v.w;
    *(bf16x4*)(dst + i) = o;
}

// ---------------- GEMM: Y[m][n] = sum_k X[m][k] * W[n][k] ----------------
#define BM 128
#define BN 128
#define BKK 64

template<int OUTF32>
__global__ __launch_bounds__(256) void gemm_bt(
    const bf16* __restrict__ X,
    const bf16* __restrict__ W0, const bf16* __restrict__ W1, const bf16* __restrict__ W2,
    void* __restrict__ Y0, int M, int N, int K)
{
    const bf16* W = (blockIdx.z == 0) ? W0 : (blockIdx.z == 1 ? W1 : W2);
    const int m0 = blockIdx.y * BM, n0 = blockIdx.x * BN;
    __shared__ bf16 lA[BM][8][8];
    __shared__ bf16 lB[BN][8][8];
    const int tid = threadIdx.x;
    const int lane = tid & 63, w = tid >> 6;
    const int l16 = lane & 15, lc = lane >> 4, l7 = lane & 7;
    const int wm = (w & 1) * 64, wn = (w >> 1) * 64;
    f32x4 acc[4][4] = {};

    for (int k0 = 0; k0 < K; k0 += BKK) {
        __syncthreads();
#pragma unroll
        for (int i = 0; i < 4; i++) {
            int uu = tid + 256 * i;
            int m = uu >> 3, c = uu & 7;
            *(float4*)(&lA[m][c ^ (m & 7)][0]) =
                *(const float4*)(X + (size_t)(m0 + m) * K + k0 + 8 * c);
            *(float4*)(&lB[m][c ^ (m & 7)][0]) =
                *(const float4*)(W + (size_t)(n0 + m) * K + k0 + 8 * c);
        }
        __syncthreads();
#pragma unroll
        for (int ks = 0; ks < 2; ks++) {
            bf16x8 af[4], bfr[4];
#pragma unroll
            for (int i = 0; i < 4; i++) {
                af[i]  = *(const bf16x8*)(&lA[wm + 16 * i + l16][(4 * ks + lc) ^ l7][0]);
                bfr[i] = *(const bf16x8*)(&lB[wn + 16 * i + l16][(4 * ks + lc) ^ l7][0]);
            }
#pragma unroll
            for (int i = 0; i < 4; i++)
#pragma unroll
                for (int j = 0; j < 4; j++)
                    acc[i][j] = __builtin_amdgcn_mfma_f32_16x16x32_bf16(
                        af[i], bfr[j], acc[i][j], 0, 0, 0);
        }
    }
    if (OUTF32) {
        float* Y = (float*)Y0;
#pragma unroll
        for (int i = 0; i < 4; i++) {
            int row = m0 + wm + 16 * i + 4 * lc;
#pragma unroll
            for (int j = 0; j < 4; j++) {
                int col = n0 + wn + 16 * j + l16;
#pragma unroll
                for (int r = 0; r < 4; r++)
                    Y[(size_t)(row + r) * N + col] = acc[i][j][r];
            }
        }
    } else {
        bf16* Y = (bf16*)Y0 + (size_t)blockIdx.z * M * N;
#pragma unroll
        for (int i = 0; i < 4; i++) {
            int row = m0 + wm + 16 * i + 4 * lc;
#pragma unroll
            for (int j = 0; j < 4; j++) {
                int col = n0 + wn + 16 * j + l16;
#pragma unroll
                for (int r = 0; r < 4; r++)
                    Y[(size_t)(row + r) * N + col] = (bf16)acc[i][j][r];
            }
        }
    }
}

// ---------------- RoPE + reshape to per-head [h][s][64] ----------------
__global__ __launch_bounds__(256) void rope_qk(
    const bf16* __restrict__ QKV, const float* __restrict__ cosT,
    const float* __restrict__ sinT, const int* __restrict__ nregp,
    bf16* __restrict__ Qh, bf16* __restrict__ Kh)
{
    const int s = blockIdx.x, t = threadIdx.x;
    const int h = t >> 5, d = t & 31;
    const int nreg = *nregp;
    float c = 1.f, sn = 0.f;
    if (s >= nreg) {
        const int p = s - nreg;
        c  = cosT[p * HD + d];
        sn = sinT[p * HD + d];
    }
    {
        const bf16* Q = QKV;
        float q0 = (float)Q[(size_t)s * HID + h * HD + d];
        float q1 = (float)Q[(size_t)s * HID + h * HD + d + 32];
        bf16* outp = Qh + ((size_t)h * S_LEN + s) * HD;
        outp[d]      = (bf16)(q0 * c - q1 * sn);
        outp[d + 32] = (bf16)(q1 * c + q0 * sn);
    }
    {
        const bf16* Kk = QKV + (size_t)S_LEN * HID;
        float k0v = (float)Kk[(size_t)s * HID + h * HD + d];
        float k1v = (float)Kk[(size_t)s * HID + h * HD + d + 32];
        bf16* outp = Kh + ((size_t)h * S_LEN + s) * HD;
        outp[d]      = (bf16)(k0v * c - k1v * sn);
        outp[d + 32] = (bf16)(k1v * c + k0v * sn);
    }
}

// ---------------- V transpose: [s][h*64+d] -> Vt[h][d][s] ----------------
__global__ __launch_bounds__(256) void v_trans(const bf16* __restrict__ QKV,
                                               bf16* __restrict__ Vt)
{
    const int s0 = blockIdx.x * 64, h = blockIdx.y;
    const bf16* V = QKV + (size_t)2 * S_LEN * HID;
    __shared__ bf16 tile[64][72];
    const int t = threadIdx.x;
#pragma unroll
    for (int i = 0; i < 2; i++) {
        int uu = t + 256 * i;
        int r = uu >> 3, cc = (uu & 7) * 8;
        *(float4*)(&tile[r][cc]) =
            *(const float4*)(V + (size_t)(s0 + r) * HID + h * HD + cc);
    }
    __syncthreads();
#pragma unroll
    for (int i = 0; i < 2; i++) {
        int uu = t + 256 * i;
        int d = uu >> 3, sc = (uu & 7) * 8;
        bf16x8 o;
#pragma unroll
        for (int j = 0; j < 8; j++) o[j] = tile[sc + j][d];
        *(bf16x8*)(Vt + ((size_t)h * HD + d) * S_LEN + s0 + sc) = o;
    }
}

// ---------------- Causal attention: 4-wave blocks, LDS-shared K/V ----------------
// Rounds 3-4 were bound at ~0.6 cache-lines/cy/CU: every wave privately
// re-read the K/V tiles through vmem (384 lines/wave-iter). Here a 256-thread
// block (4 waves, 64 q-rows, 16 per wave) stages each 8KB K and V tile into
// LDS ONCE (16 coalesced wave-loads/block-iter, 6x less vmem), double-buffered
// so tile t+1 loads overlap tile t compute; ONE barrier per k-tile (writes to
// buf^1 after the barrier cannot race reads of buf^1, which all precede it).
// Softmax stays the S^T no-max per-lane form from round 3 (VALU-cheap).
__global__ __launch_bounds__(256) void attn(
    const bf16* __restrict__ Qh, const bf16* __restrict__ Kh,
    const bf16* __restrict__ Vt, bf16* __restrict__ Ob)
{
    const int h = blockIdx.x;
    const int bt = 63 - (int)blockIdx.y;     // longest-first (LPT)
    const int qb = bt * 64;                  // block's 64 q-rows
    const int nkt = bt + 1;                  // 64-key tiles
    __shared__ bf16 lK[2][64][8][8];         // [buf][key_row][chunk^swz][8]
    __shared__ bf16 lV[2][64][8][8];         // [buf][d_row][chunk^swz][8]
    __shared__ bf16 lPT[4][16][76];          // per-wave P^T [q][key]
    const int tid = threadIdx.x;
    const int lane = tid & 63, w = tid >> 6;
    const int l16 = lane & 15, lc = lane >> 4, l7 = lane & 7;

    const bf16* Kb_ = Kh + (size_t)h * S_LEN * HD;
    const bf16* Vb_ = Vt + (size_t)h * HD * S_LEN;

    // staging unit for this thread: uu = tid + 256*i, i=0..1 -> 512 units
    // K unit: row n = uu>>3 (key), chunk c = uu&7 ; V unit: row d, chunk c
    int srow[2], scol[2];
#pragma unroll
    for (int i = 0; i < 2; i++) {
        int uu = tid + 256 * i;
        srow[i] = uu >> 3;
        scol[i] = uu & 7;
    }

    // q fragments (B-operand), rows qb+16w+l16
    bf16x8 qf[2];
    {
        const bf16* qrow = Qh + (size_t)h * S_LEN * HD + (size_t)(qb + 16 * w + l16) * HD;
        qf[0] = *(const bf16x8*)(qrow + 8 * lc);
        qf[1] = *(const bf16x8*)(qrow + 32 + 8 * lc);
    }
    f32x4 oacc[4] = {};
    float l_sum = 0.f;

    // prologue: stage tile 0 into buf 0
    {
        bf16x8 kr[2], vr[2];
#pragma unroll
        for (int i = 0; i < 2; i++) {
            kr[i] = *(const bf16x8*)(Kb_ + (size_t)srow[i] * HD + 8 * scol[i]);
            vr[i] = *(const bf16x8*)(Vb_ + (size_t)srow[i] * S_LEN + 8 * scol[i]);
        }
#pragma unroll
        for (int i = 0; i < 2; i++) {
            *(bf16x8*)(&lK[0][srow[i]][scol[i] ^ (srow[i] & 7)][0]) = kr[i];
            *(bf16x8*)(&lV[0][srow[i]][scol[i] ^ (srow[i] & 7)][0]) = vr[i];
        }
    }

    int cur = 0;
    for (int kt = 0; kt < nkt; kt++) {
        __syncthreads();   // buf[cur] staged; everyone done reading buf[cur^1]

        // issue next tile's global loads (consumed at end of this iter)
        bf16x8 kr[2], vr[2];
        if (kt + 1 < nkt) {
#pragma unroll
            for (int i = 0; i < 2; i++) {
                kr[i] = *(const bf16x8*)(Kb_ + (size_t)((kt + 1) * 64 + srow[i]) * HD +
                                         8 * scol[i]);
                vr[i] = *(const bf16x8*)(Vb_ + (size_t)srow[i] * S_LEN +
                                         (kt + 1) * 64 + 8 * scol[i]);
            }
        }

        // S^T = K Q^T : sacc[j] rows = keys 16j+4lc+r, col = q = l16
        f32x4 sacc[4] = {};
#pragma unroll
        for (int ks = 0; ks < 2; ks++)
#pragma unroll
            for (int j = 0; j < 4; j++) {
                bf16x8 kf = *(const bf16x8*)(&lK[cur][16 * j + l16][(4 * ks + lc) ^ l7][0]);
                sacc[j] = __builtin_amdgcn_mfma_f32_16x16x32_bf16(
                    kf, qf[ks], sacc[j], 0, 0, 0);
            }

        // p = exp2(s*scale); mask key>q on the last (diagonal) tile
        float pv[4][4];
#pragma unroll
        for (int j = 0; j < 4; j++)
#pragma unroll
            for (int r = 0; r < 4; r++)
                pv[j][r] = __builtin_amdgcn_exp2f(sacc[j][r] * SCALE_LOG2E);
        if (kt == nkt - 1) {
            const int qg = qb + 16 * w + l16;
#pragma unroll
            for (int j = 0; j < 4; j++)
#pragma unroll
                for (int r = 0; r < 4; r++) {
                    const int keyg = kt * 64 + 16 * j + 4 * lc + r;
                    if (keyg > qg) pv[j][r] = 0.f;
                }
        }
#pragma unroll
        for (int j = 0; j < 4; j++)
            l_sum += (pv[j][0] + pv[j][1]) + (pv[j][2] + pv[j][3]);

        // P^T -> per-wave LDS (no barrier: single-wave ds ordering)
#pragma unroll
        for (int j = 0; j < 4; j++) {
            bf16x4 pp;
#pragma unroll
            for (int r = 0; r < 4; r++) pp[r] = (bf16)pv[j][r];
            *(bf16x4*)(&lPT[w][l16][16 * j + 4 * lc]) = pp;
        }
        bf16x8 pb[2];
#pragma unroll
        for (int ks = 0; ks < 2; ks++)
            pb[ks] = *(const bf16x8*)(&lPT[w][l16][32 * ks + 8 * lc]);

        // O^T += V^T P^T
#pragma unroll
        for (int ks = 0; ks < 2; ks++)
#pragma unroll
            for (int j = 0; j < 4; j++) {
                bf16x8 vf = *(const bf16x8*)(&lV[cur][16 * j + l16][(4 * ks + lc) ^ l7][0]);
                oacc[j] = __builtin_amdgcn_mfma_f32_16x16x32_bf16(
                    vf, pb[ks], oacc[j], 0, 0, 0);
            }

        // write next tile into the other buffer (post-barrier: race-free)
        if (kt + 1 < nkt) {
#pragma unroll
            for (int i = 0; i < 2; i++) {
                *(bf16x8*)(&lK[cur ^ 1][srow[i]][scol[i] ^ (srow[i] & 7)][0]) = kr[i];
                *(bf16x8*)(&lV[cur ^ 1][srow[i]][scol[i] ^ (srow[i] & 7)][0]) = vr[i];
            }
        }
        cur ^= 1;
    }

    // l: combine the 4 lc-replicas of each q
    l_sum += __shfl_xor(l_sum, 16, 64);
    l_sum += __shfl_xor(l_sum, 32, 64);
    const float inv = 1.0f / l_sum;

    // O^T C-layout: lane holds d=16j+4lc+r for q=l16 -> row qb+16w+l16
    bf16* orow = Ob + (size_t)(qb + 16 * w + l16) * HID + h * HD;
#pragma unroll
    for (int j = 0; j < 4; j++) {
        bf16x4 o4;
#pragma unroll
        for (int r = 0; r < 4; r++) o4[r] = (bf16)(oacc[j][r] * inv);
        *(bf16x4*)(orow + 16 * j + 4 * lc) = o4;
    }
}

// ---------------- launch ----------------
extern "C" void kernel_launch(void* const* d_in, const int* in_sizes, int n_in,
                              void* d_out, int out_size, void* d_ws, size_t ws_size,
                              hipStream_t stream) {
    const float* hs   = (const float*)d_in[0];
    const float* Wq   = (const float*)d_in[1];
    const float* Wk   = (const float*)d_in[2];
    const float* Wv   = (const float*)d_in[3];
    const float* Wo   = (const float*)d_in[4];
    const float* cosT = (const float*)d_in[5];
    const float* sinT = (const float*)d_in[6];
    const int*   nreg = (const int*)d_in[7];

    char* ws = (char*)d_ws;
    const size_t MiB = 1 << 20;
    bf16* Xb   = (bf16*)(ws);                         // 0-4 MiB
    bf16* Wqb  = (bf16*)(ws + 4 * MiB);               // 4-6 MiB weights
    bf16* Wkb  = (bf16*)(ws + 4 * MiB + 512 * 1024);
    bf16* Wvb  = (bf16*)(ws + 5 * MiB);
    bf16* Wob  = (bf16*)(ws + 5 * MiB + 512 * 1024);
    bf16* QKVf = (bf16*)(ws + 6 * MiB);               // 6-18 MiB
    bf16* Qh   = (bf16*)(ws + 22 * MiB);              // 22-26
    bf16* Kh   = (bf16*)(ws + 26 * MiB);              // 26-30
    bf16* Vt   = (bf16*)(ws + 30 * MiB);              // 30-34
    bf16* Ob   = (bf16*)(ws + 34 * MiB);              // 34-38

    cvt_f32_bf16<<<2048, 256, 0, stream>>>(hs, Xb, S_LEN * HID);
    cvt_w4<<<dim3(256, 4), 256, 0, stream>>>(Wq, Wk, Wv, Wo, Wqb, Wkb, Wvb, Wob);

    gemm_bt<0><<<dim3(4, 32, 3), 256, 0, stream>>>(Xb, Wqb, Wkb, Wvb,
                                                   (void*)QKVf, S_LEN, HID, HID);
    rope_qk<<<4096, 256, 0, stream>>>(QKVf, cosT, sinT, nreg, Qh, Kh);
    v_trans<<<dim3(64, 8), 256, 0, stream>>>(QKVf, Vt);
    attn<<<dim3(8, 64), 256, 0, stream>>>(Qh, Kh, Vt, Ob);
    gemm_bt<1><<<dim3(4, 32, 1), 256, 0, stream>>>(Ob, Wob, Wob, Wob,
                                                   d_out, S_LEN, HID, HID);
}

// Round 6
// 148.780 us; speedup vs baseline: 1.6594x; 1.1510x over previous
//
#include <hip/hip_runtime.h>
#include <cstdint>
#include <cstddef>

#define S_LEN 4096
#define HID   512
#define NHEAD 8
#define HD    64
// (1/sqrt(64)) * log2(e)
#define SCALE_LOG2E 0.1803368801111204f

typedef __bf16 bf16;
typedef __bf16 bf16x8 __attribute__((ext_vector_type(8)));
typedef __bf16 bf16x4 __attribute__((ext_vector_type(4)));
typedef float  f32x4  __attribute__((ext_vector_type(4)));

// ---------------- fp32 -> bf16 conversion ----------------
__global__ __launch_bounds__(256) void cvt_f32_bf16(const float* __restrict__ src,
                                                    bf16* __restrict__ dst, int n) {
    int i = (blockIdx.x * 256 + threadIdx.x) * 4;
    if (i + 3 < n) {
        const float4 v = *(const float4*)(src + i);
        bf16x4 o;
        o[0] = (bf16)v.x; o[1] = (bf16)v.y; o[2] = (bf16)v.z; o[3] = (bf16)v.w;
        *(bf16x4*)(dst + i) = o;
    }
}

// 4 weight matrices (512x512 each) in one launch.
__global__ __launch_bounds__(256) void cvt_w4(
    const float* __restrict__ s0, const float* __restrict__ s1,
    const float* __restrict__ s2, const float* __restrict__ s3,
    bf16* __restrict__ d0, bf16* __restrict__ d1,
    bf16* __restrict__ d2, bf16* __restrict__ d3) {
    const float* src; bf16* dst;
    switch (blockIdx.y) {
        case 0: src = s0; dst = d0; break;
        case 1: src = s1; dst = d1; break;
        case 2: src = s2; dst = d2; break;
        default: src = s3; dst = d3; break;
    }
    int i = (blockIdx.x * 256 + threadIdx.x) * 4;
    const float4 v = *(const float4*)(src + i);
    bf16x4 o;
    o[0] = (bf16)v.x; o[1] = (bf16)v.y; o[2] = (bf16)v.z; o[3] = (bf16)v.w;
    *(bf16x4*)(dst + i) = o;
}

#define BM 128
#define BN 128
#define BKK 64

// ---------------- QKV GEMM with fused RoPE + layout epilogue ----------------
// z=0: Q -> rope -> Qh[h][s][64]; z=1: K -> rope -> Kh[h][s][64];
// z=2: V -> transpose -> Vt[h][d][s].
// C-layout: lane(l16,lc), acc[i][j][r] -> row m0+wm+16i+4lc+r, col n0+wn+16j+l16.
// RoPE pairs (d, d+32) = (j, j+2) of the SAME lane; cos/sin table duplicated
// (cos[p][d+32]==cos[p][d]) so one cos/sin per pair, applied on fp32 acc.
__global__ __launch_bounds__(256) void gemm_qkv(
    const bf16* __restrict__ X,
    const bf16* __restrict__ W0, const bf16* __restrict__ W1, const bf16* __restrict__ W2,
    const float* __restrict__ cosT, const float* __restrict__ sinT,
    const int* __restrict__ nregp,
    bf16* __restrict__ Qh, bf16* __restrict__ Kh, bf16* __restrict__ Vt)
{
    const int z = blockIdx.z;
    const bf16* W = (z == 0) ? W0 : (z == 1 ? W1 : W2);
    const int m0 = blockIdx.y * BM, n0 = blockIdx.x * BN;
    __shared__ bf16 lA[BM][8][8];
    __shared__ bf16 lB[BN][8][8];
    const int tid = threadIdx.x;
    const int lane = tid & 63, w = tid >> 6;
    const int l16 = lane & 15, lc = lane >> 4, l7 = lane & 7;
    const int wm = (w & 1) * 64, wn = (w >> 1) * 64;
    f32x4 acc[4][4] = {};

    for (int k0 = 0; k0 < HID; k0 += BKK) {
        __syncthreads();
#pragma unroll
        for (int i = 0; i < 4; i++) {
            int uu = tid + 256 * i;
            int m = uu >> 3, c = uu & 7;
            *(float4*)(&lA[m][c ^ (m & 7)][0]) =
                *(const float4*)(X + (size_t)(m0 + m) * HID + k0 + 8 * c);
            *(float4*)(&lB[m][c ^ (m & 7)][0]) =
                *(const float4*)(W + (size_t)(n0 + m) * HID + k0 + 8 * c);
        }
        __syncthreads();
#pragma unroll
        for (int ks = 0; ks < 2; ks++) {
            bf16x8 af[4], bfr[4];
#pragma unroll
            for (int i = 0; i < 4; i++) {
                af[i]  = *(const bf16x8*)(&lA[wm + 16 * i + l16][(4 * ks + lc) ^ l7][0]);
                bfr[i] = *(const bf16x8*)(&lB[wn + 16 * i + l16][(4 * ks + lc) ^ l7][0]);
            }
#pragma unroll
            for (int i = 0; i < 4; i++)
#pragma unroll
                for (int j = 0; j < 4; j++)
                    acc[i][j] = __builtin_amdgcn_mfma_f32_16x16x32_bf16(
                        af[i], bfr[j], acc[i][j], 0, 0, 0);
        }
    }

    const int h = (n0 + wn) >> 6;            // 64-col group = one head
    if (z == 2) {
        // V: Vt[h][dl][s], r gives 4 consecutive s -> bf16x4
#pragma unroll
        for (int i = 0; i < 4; i++) {
            const int s0r = m0 + wm + 16 * i + 4 * lc;
#pragma unroll
            for (int j = 0; j < 4; j++) {
                const int dl = 16 * j + l16;
                bf16x4 o;
#pragma unroll
                for (int r = 0; r < 4; r++) o[r] = (bf16)acc[i][j][r];
                *(bf16x4*)(Vt + ((size_t)(h * HD + dl)) * S_LEN + s0r) = o;
            }
        }
    } else {
        const int nreg = *nregp;
        bf16* dst = (z == 0) ? Qh : Kh;
#pragma unroll
        for (int i = 0; i < 4; i++) {
            const int s0r = m0 + wm + 16 * i + 4 * lc;
#pragma unroll
            for (int r = 0; r < 4; r++) {
                const int s = s0r + r;
                float c0 = 1.f, sn0 = 0.f, c1 = 1.f, sn1 = 0.f;
                if (s >= nreg) {
                    const int p = s - nreg;
                    c0  = cosT[(size_t)p * HD + l16];
                    sn0 = sinT[(size_t)p * HD + l16];
                    c1  = cosT[(size_t)p * HD + 16 + l16];
                    sn1 = sinT[(size_t)p * HD + 16 + l16];
                }
                const float x0 = acc[i][0][r], x1 = acc[i][1][r];
                const float x2 = acc[i][2][r], x3 = acc[i][3][r];
                bf16* row = dst + ((size_t)h * S_LEN + s) * HD;
                row[l16]      = (bf16)(x0 * c0 - x2 * sn0);
                row[l16 + 16] = (bf16)(x1 * c1 - x3 * sn1);
                row[l16 + 32] = (bf16)(x2 * c0 + x0 * sn0);
                row[l16 + 48] = (bf16)(x3 * c1 + x1 * sn1);
            }
        }
    }
}

// ---------------- plain GEMM (output projection), fp32 out ----------------
__global__ __launch_bounds__(256) void gemm_out(
    const bf16* __restrict__ X, const bf16* __restrict__ W,
    float* __restrict__ Y)
{
    const int m0 = blockIdx.y * BM, n0 = blockIdx.x * BN;
    __shared__ bf16 lA[BM][8][8];
    __shared__ bf16 lB[BN][8][8];
    const int tid = threadIdx.x;
    const int lane = tid & 63, w = tid >> 6;
    const int l16 = lane & 15, lc = lane >> 4, l7 = lane & 7;
    const int wm = (w & 1) * 64, wn = (w >> 1) * 64;
    f32x4 acc[4][4] = {};

    for (int k0 = 0; k0 < HID; k0 += BKK) {
        __syncthreads();
#pragma unroll
        for (int i = 0; i < 4; i++) {
            int uu = tid + 256 * i;
            int m = uu >> 3, c = uu & 7;
            *(float4*)(&lA[m][c ^ (m & 7)][0]) =
                *(const float4*)(X + (size_t)(m0 + m) * HID + k0 + 8 * c);
            *(float4*)(&lB[m][c ^ (m & 7)][0]) =
                *(const float4*)(W + (size_t)(n0 + m) * HID + k0 + 8 * c);
        }
        __syncthreads();
#pragma unroll
        for (int ks = 0; ks < 2; ks++) {
            bf16x8 af[4], bfr[4];
#pragma unroll
            for (int i = 0; i < 4; i++) {
                af[i]  = *(const bf16x8*)(&lA[wm + 16 * i + l16][(4 * ks + lc) ^ l7][0]);
                bfr[i] = *(const bf16x8*)(&lB[wn + 16 * i + l16][(4 * ks + lc) ^ l7][0]);
            }
#pragma unroll
            for (int i = 0; i < 4; i++)
#pragma unroll
                for (int j = 0; j < 4; j++)
                    acc[i][j] = __builtin_amdgcn_mfma_f32_16x16x32_bf16(
                        af[i], bfr[j], acc[i][j], 0, 0, 0);
        }
    }
#pragma unroll
    for (int i = 0; i < 4; i++) {
        int row = m0 + wm + 16 * i + 4 * lc;
#pragma unroll
        for (int j = 0; j < 4; j++) {
            int col = n0 + wn + 16 * j + l16;
#pragma unroll
            for (int r = 0; r < 4; r++)
                Y[(size_t)(row + r) * HID + col] = acc[i][j][r];
        }
    }
}

// ---------------- Causal attention: 4-wave LDS-shared blocks, key-split x2 ----
// Round-5 structure (LDS-staged K/V, double-buffered, S^T no-max softmax) was
// critical-path-bound: longest block = 64 iters x ~2000cy = 53us. Split each
// q-block's key range into 2 chunks (grid x = h*2+chunk); the no-max softmax
// partials combine by pure addition (unnormalized O^T fp32 + l), so chunks are
// independent -> longest chain 32 iters, 1024 blocks (~4/CU dispatched).
__global__ __launch_bounds__(256) void attn_part(
    const bf16* __restrict__ Qh, const bf16* __restrict__ Kh,
    const bf16* __restrict__ Vt, float* __restrict__ Opart,
    float* __restrict__ Lpart)
{
    const int h = blockIdx.x >> 1;
    const int ch = blockIdx.x & 1;
    const int bt = 63 - (int)blockIdx.y;     // longest-first (LPT)
    const int qb = bt * 64;
    const int nkt = bt + 1;
    const int kmid = nkt >> 1;
    const int k0 = ch ? kmid : 0;
    const int k1 = ch ? nkt : kmid;
    const int tid = threadIdx.x;
    const int lane = tid & 63, w = tid >> 6;
    const int l16 = lane & 15, lc = lane >> 4, l7 = lane & 7;

    float* Op = Opart + ((size_t)(h * 64 + bt) * 2 + ch) * 4096;
    float* Lp = Lpart + ((size_t)(h * 64 + bt) * 2 + ch) * 64;

    if (k0 >= k1) {                          // empty chunk (bt=0, ch=0)
        const f32x4 z = {0.f, 0.f, 0.f, 0.f};
#pragma unroll
        for (int i = 0; i < 4; i++)
            *(f32x4*)(Op + 4 * (tid + 256 * i)) = z;
        if (tid < 64) Lp[tid] = 0.f;
        return;
    }

    __shared__ bf16 lK[2][64][8][8];
    __shared__ bf16 lV[2][64][8][8];
    __shared__ bf16 lPT[4][16][76];

    const bf16* Kb_ = Kh + (size_t)h * S_LEN * HD;
    const bf16* Vb_ = Vt + (size_t)h * HD * S_LEN;

    int srow[2], scol[2];
#pragma unroll
    for (int i = 0; i < 2; i++) {
        int uu = tid + 256 * i;
        srow[i] = uu >> 3;
        scol[i] = uu & 7;
    }

    bf16x8 qf[2];
    {
        const bf16* qrow = Qh + (size_t)h * S_LEN * HD + (size_t)(qb + 16 * w + l16) * HD;
        qf[0] = *(const bf16x8*)(qrow + 8 * lc);
        qf[1] = *(const bf16x8*)(qrow + 32 + 8 * lc);
    }
    f32x4 oacc[4] = {};
    float l_sum = 0.f;

    // prologue: stage tile k0 into buf 0
    {
        bf16x8 kr[2], vr[2];
#pragma unroll
        for (int i = 0; i < 2; i++) {
            kr[i] = *(const bf16x8*)(Kb_ + (size_t)(k0 * 64 + srow[i]) * HD + 8 * scol[i]);
            vr[i] = *(const bf16x8*)(Vb_ + (size_t)srow[i] * S_LEN + k0 * 64 + 8 * scol[i]);
        }
#pragma unroll
        for (int i = 0; i < 2; i++) {
            *(bf16x8*)(&lK[0][srow[i]][scol[i] ^ (srow[i] & 7)][0]) = kr[i];
            *(bf16x8*)(&lV[0][srow[i]][scol[i] ^ (srow[i] & 7)][0]) = vr[i];
        }
    }

    int cur = 0;
    for (int kt = k0; kt < k1; kt++) {
        __syncthreads();

        bf16x8 kr[2], vr[2];
        if (kt + 1 < k1) {
#pragma unroll
            for (int i = 0; i < 2; i++) {
                kr[i] = *(const bf16x8*)(Kb_ + (size_t)((kt + 1) * 64 + srow[i]) * HD +
                                         8 * scol[i]);
                vr[i] = *(const bf16x8*)(Vb_ + (size_t)srow[i] * S_LEN +
                                         (kt + 1) * 64 + 8 * scol[i]);
            }
        }

        // S^T = K Q^T
        f32x4 sacc[4] = {};
#pragma unroll
        for (int ks = 0; ks < 2; ks++)
#pragma unroll
            for (int j = 0; j < 4; j++) {
                bf16x8 kf = *(const bf16x8*)(&lK[cur][16 * j + l16][(4 * ks + lc) ^ l7][0]);
                sacc[j] = __builtin_amdgcn_mfma_f32_16x16x32_bf16(
                    kf, qf[ks], sacc[j], 0, 0, 0);
            }

        float pv[4][4];
#pragma unroll
        for (int j = 0; j < 4; j++)
#pragma unroll
            for (int r = 0; r < 4; r++)
                pv[j][r] = __builtin_amdgcn_exp2f(sacc[j][r] * SCALE_LOG2E);
        if (kt == nkt - 1) {                 // diagonal tile (always in last chunk)
            const int qg = qb + 16 * w + l16;
#pragma unroll
            for (int j = 0; j < 4; j++)
#pragma unroll
                for (int r = 0; r < 4; r++) {
                    const int keyg = kt * 64 + 16 * j + 4 * lc + r;
                    if (keyg > qg) pv[j][r] = 0.f;
                }
        }
#pragma unroll
        for (int j = 0; j < 4; j++)
            l_sum += (pv[j][0] + pv[j][1]) + (pv[j][2] + pv[j][3]);

#pragma unroll
        for (int j = 0; j < 4; j++) {
            bf16x4 pp;
#pragma unroll
            for (int r = 0; r < 4; r++) pp[r] = (bf16)pv[j][r];
            *(bf16x4*)(&lPT[w][l16][16 * j + 4 * lc]) = pp;
        }
        bf16x8 pb[2];
#pragma unroll
        for (int ks = 0; ks < 2; ks++)
            pb[ks] = *(const bf16x8*)(&lPT[w][l16][32 * ks + 8 * lc]);

        // O^T += V^T P^T
#pragma unroll
        for (int ks = 0; ks < 2; ks++)
#pragma unroll
            for (int j = 0; j < 4; j++) {
                bf16x8 vf = *(const bf16x8*)(&lV[cur][16 * j + l16][(4 * ks + lc) ^ l7][0]);
                oacc[j] = __builtin_amdgcn_mfma_f32_16x16x32_bf16(
                    vf, pb[ks], oacc[j], 0, 0, 0);
            }

        if (kt + 1 < k1) {
#pragma unroll
            for (int i = 0; i < 2; i++) {
                *(bf16x8*)(&lK[cur ^ 1][srow[i]][scol[i] ^ (srow[i] & 7)][0]) = kr[i];
                *(bf16x8*)(&lV[cur ^ 1][srow[i]][scol[i] ^ (srow[i] & 7)][0]) = vr[i];
            }
        }
        cur ^= 1;
    }

    // l: combine 4 lc-replicas of each q
    l_sum += __shfl_xor(l_sum, 16, 64);
    l_sum += __shfl_xor(l_sum, 32, 64);
    if (lane < 16) Lp[16 * w + l16] = l_sum;

    // unnormalized O^T partial: Op[q*64+d], lane holds d=16j+4lc+r, q=16w+l16
#pragma unroll
    for (int j = 0; j < 4; j++)
        *(f32x4*)(Op + (size_t)(16 * w + l16) * 64 + 16 * j + 4 * lc) = oacc[j];
}

// combine: O = (O0+O1)/(l0+l1) -> bf16 Ob[s][h*64+d]
__global__ __launch_bounds__(256) void attn_combine(
    const float* __restrict__ Opart, const float* __restrict__ Lpart,
    bf16* __restrict__ Ob)
{
    const int h = blockIdx.x, bt = blockIdx.y;
    const size_t base = (size_t)(h * 64 + bt) * 2;
    const float* O0 = Opart + base * 4096;
    const float* O1 = O0 + 4096;
    const float* L0 = Lpart + base * 64;
    const int t = threadIdx.x;
    const int q = t >> 2, dq = (t & 3) * 16;
    const float l = L0[q] + L0[64 + q];
    const float inv = 1.0f / l;
    bf16* out = Ob + (size_t)(bt * 64 + q) * HID + h * HD + dq;
#pragma unroll
    for (int g = 0; g < 2; g++) {
        bf16x8 o8;
#pragma unroll
        for (int e = 0; e < 2; e++) {
            f32x4 a = *(const f32x4*)(O0 + q * 64 + dq + 8 * g + 4 * e);
            f32x4 b = *(const f32x4*)(O1 + q * 64 + dq + 8 * g + 4 * e);
#pragma unroll
            for (int r = 0; r < 4; r++) o8[4 * e + r] = (bf16)((a[r] + b[r]) * inv);
        }
        *(bf16x8*)(out + 8 * g) = o8;
    }
}

// ---------------- launch ----------------
extern "C" void kernel_launch(void* const* d_in, const int* in_sizes, int n_in,
                              void* d_out, int out_size, void* d_ws, size_t ws_size,
                              hipStream_t stream) {
    const float* hs   = (const float*)d_in[0];
    const float* Wq   = (const float*)d_in[1];
    const float* Wk   = (const float*)d_in[2];
    const float* Wv   = (const float*)d_in[3];
    const float* Wo   = (const float*)d_in[4];
    const float* cosT = (const float*)d_in[5];
    const float* sinT = (const float*)d_in[6];
    const int*   nreg = (const int*)d_in[7];

    char* ws = (char*)d_ws;
    const size_t MiB = 1 << 20;
    bf16*  Xb    = (bf16*)(ws);                         // 0-4 MiB
    bf16*  Wqb   = (bf16*)(ws + 4 * MiB);               // 4-6 MiB weights
    bf16*  Wkb   = (bf16*)(ws + 4 * MiB + 512 * 1024);
    bf16*  Wvb   = (bf16*)(ws + 5 * MiB);
    bf16*  Wob   = (bf16*)(ws + 5 * MiB + 512 * 1024);
    bf16*  Qh    = (bf16*)(ws + 6 * MiB);               // 6-10  [8][S][64]
    bf16*  Kh    = (bf16*)(ws + 10 * MiB);              // 10-14 [8][S][64]
    bf16*  Vt    = (bf16*)(ws + 14 * MiB);              // 14-18 [8][64][S]
    bf16*  Ob    = (bf16*)(ws + 18 * MiB);              // 18-22 [S][512]
    float* Opart = (float*)(ws + 22 * MiB);             // 22-38 (1024 x 16KB)
    float* Lpart = (float*)(ws + 38 * MiB);             // 38-38.26

    cvt_f32_bf16<<<2048, 256, 0, stream>>>(hs, Xb, S_LEN * HID);
    cvt_w4<<<dim3(256, 4), 256, 0, stream>>>(Wq, Wk, Wv, Wo, Wqb, Wkb, Wvb, Wob);

    gemm_qkv<<<dim3(4, 32, 3), 256, 0, stream>>>(Xb, Wqb, Wkb, Wvb,
                                                 cosT, sinT, nreg, Qh, Kh, Vt);
    attn_part<<<dim3(16, 64), 256, 0, stream>>>(Qh, Kh, Vt, Opart, Lpart);
    attn_combine<<<dim3(8, 64), 256, 0, stream>>>(Opart, Lpart, Ob);
    gemm_out<<<dim3(4, 32), 256, 0, stream>>>(Ob, Wob, (float*)d_out);
}

// Round 7
// 148.779 us; speedup vs baseline: 1.6594x; 1.0000x over previous
//
#include <hip/hip_runtime.h>
#include <cstdint>
#include <cstddef>

#define S_LEN 4096
#define HID   512
#define NHEAD 8
#define HD    64
// (1/sqrt(64)) * log2(e)
#define SCALE_LOG2E 0.1803368801111204f

typedef __bf16 bf16;
typedef __bf16 bf16x8 __attribute__((ext_vector_type(8)));
typedef __bf16 bf16x4 __attribute__((ext_vector_type(4)));
typedef float  f32x4  __attribute__((ext_vector_type(4)));

__device__ __forceinline__ bf16x8 cvt8(float4 a, float4 b) {
    bf16x8 o;
    o[0] = (bf16)a.x; o[1] = (bf16)a.y; o[2] = (bf16)a.z; o[3] = (bf16)a.w;
    o[4] = (bf16)b.x; o[5] = (bf16)b.y; o[6] = (bf16)b.z; o[7] = (bf16)b.w;
    return o;
}

// ---------------- QKV GEMM, fp32 inputs, fused cvt + RoPE/transpose epilogue ----
// BM=64 x BN=128, 4 waves in 2x2 (wave rows 32, cols 64 head-aligned so RoPE
// pairs (d,d+32) stay in-lane). grid (4,64,3) = 768 blocks (~3/CU) vs round-6's
// 384: the 128-tile GEMMs ran at 0.5-1.5 blocks/CU and dominated the hidden
// ~105us. fp32->bf16 conversion fused into LDS staging (cvt kernels deleted).
__global__ __launch_bounds__(256) void gemm_qkv(
    const float* __restrict__ Xf,
    const float* __restrict__ W0, const float* __restrict__ W1, const float* __restrict__ W2,
    const float* __restrict__ cosT, const float* __restrict__ sinT,
    const int* __restrict__ nregp,
    bf16* __restrict__ Qh, bf16* __restrict__ Kh, bf16* __restrict__ Vt)
{
    const int z = blockIdx.z;
    const float* W = (z == 0) ? W0 : (z == 1 ? W1 : W2);
    const int m0 = blockIdx.y * 64, n0 = blockIdx.x * 128;
    __shared__ bf16 lA[64][8][8];
    __shared__ bf16 lB[128][8][8];
    const int tid = threadIdx.x;
    const int lane = tid & 63, w = tid >> 6;
    const int l16 = lane & 15, lc = lane >> 4, l7 = lane & 7;
    const int wm = (w & 1) * 32, wn = (w >> 1) * 64;
    f32x4 acc[2][4] = {};

    for (int k0 = 0; k0 < HID; k0 += 64) {
        __syncthreads();
#pragma unroll
        for (int i = 0; i < 2; i++) {          // A: 512 units (64 rows x 8 chunks)
            int uu = tid + 256 * i;
            int m = uu >> 3, c = uu & 7;
            const float* p = Xf + (size_t)(m0 + m) * HID + k0 + 8 * c;
            *(bf16x8*)(&lA[m][c ^ (m & 7)][0]) =
                cvt8(*(const float4*)p, *(const float4*)(p + 4));
        }
#pragma unroll
        for (int i = 0; i < 4; i++) {          // B: 1024 units (128 rows x 8 chunks)
            int uu = tid + 256 * i;
            int m = uu >> 3, c = uu & 7;
            const float* p = W + (size_t)(n0 + m) * HID + k0 + 8 * c;
            *(bf16x8*)(&lB[m][c ^ (m & 7)][0]) =
                cvt8(*(const float4*)p, *(const float4*)(p + 4));
        }
        __syncthreads();
#pragma unroll
        for (int ks = 0; ks < 2; ks++) {
            bf16x8 af[2], bfr[4];
#pragma unroll
            for (int i = 0; i < 2; i++)
                af[i]  = *(const bf16x8*)(&lA[wm + 16 * i + l16][(4 * ks + lc) ^ l7][0]);
#pragma unroll
            for (int j = 0; j < 4; j++)
                bfr[j] = *(const bf16x8*)(&lB[wn + 16 * j + l16][(4 * ks + lc) ^ l7][0]);
#pragma unroll
            for (int i = 0; i < 2; i++)
#pragma unroll
                for (int j = 0; j < 4; j++)
                    acc[i][j] = __builtin_amdgcn_mfma_f32_16x16x32_bf16(
                        af[i], bfr[j], acc[i][j], 0, 0, 0);
        }
    }

    const int h = (n0 + wn) >> 6;              // wave owns one 64-col head group
    if (z == 2) {
        // V: Vt[h][d][s], r = 4 consecutive s -> bf16x4 store
#pragma unroll
        for (int i = 0; i < 2; i++) {
            const int s0r = m0 + wm + 16 * i + 4 * lc;
#pragma unroll
            for (int j = 0; j < 4; j++) {
                const int dl = 16 * j + l16;
                bf16x4 o;
#pragma unroll
                for (int r = 0; r < 4; r++) o[r] = (bf16)acc[i][j][r];
                *(bf16x4*)(Vt + ((size_t)(h * HD + dl)) * S_LEN + s0r) = o;
            }
        }
    } else {
        const int nreg = *nregp;
        bf16* dst = (z == 0) ? Qh : Kh;
#pragma unroll
        for (int i = 0; i < 2; i++) {
            const int s0r = m0 + wm + 16 * i + 4 * lc;
#pragma unroll
            for (int r = 0; r < 4; r++) {
                const int s = s0r + r;
                float c0 = 1.f, sn0 = 0.f, c1 = 1.f, sn1 = 0.f;
                if (s >= nreg) {
                    const int p = s - nreg;
                    c0  = cosT[(size_t)p * HD + l16];
                    sn0 = sinT[(size_t)p * HD + l16];
                    c1  = cosT[(size_t)p * HD + 16 + l16];
                    sn1 = sinT[(size_t)p * HD + 16 + l16];
                }
                const float x0 = acc[i][0][r], x1 = acc[i][1][r];
                const float x2 = acc[i][2][r], x3 = acc[i][3][r];
                bf16* row = dst + ((size_t)h * S_LEN + s) * HD;
                row[l16]      = (bf16)(x0 * c0 - x2 * sn0);
                row[l16 + 16] = (bf16)(x1 * c1 - x3 * sn1);
                row[l16 + 32] = (bf16)(x2 * c0 + x0 * sn0);
                row[l16 + 48] = (bf16)(x3 * c1 + x1 * sn1);
            }
        }
    }
}

// ---------------- output GEMM: bf16 A x fp32 W (fused cvt), fp32 out ----------
// BM=BN=64, 4 waves 2x2 (32x32 each), grid (8,64)=512 blocks (~2/CU).
__global__ __launch_bounds__(256) void gemm_out(
    const bf16* __restrict__ X, const float* __restrict__ Wf,
    float* __restrict__ Y)
{
    const int m0 = blockIdx.y * 64, n0 = blockIdx.x * 64;
    __shared__ bf16 lA[64][8][8];
    __shared__ bf16 lB[64][8][8];
    const int tid = threadIdx.x;
    const int lane = tid & 63, w = tid >> 6;
    const int l16 = lane & 15, lc = lane >> 4, l7 = lane & 7;
    const int wm = (w & 1) * 32, wn = (w >> 1) * 32;
    f32x4 acc[2][2] = {};

    for (int k0 = 0; k0 < HID; k0 += 64) {
        __syncthreads();
#pragma unroll
        for (int i = 0; i < 2; i++) {          // A: 512 units, bf16 source
            int uu = tid + 256 * i;
            int m = uu >> 3, c = uu & 7;
            *(bf16x8*)(&lA[m][c ^ (m & 7)][0]) =
                *(const bf16x8*)(X + (size_t)(m0 + m) * HID + k0 + 8 * c);
        }
#pragma unroll
        for (int i = 0; i < 2; i++) {          // B: 512 units, fp32 source
            int uu = tid + 256 * i;
            int m = uu >> 3, c = uu & 7;
            const float* p = Wf + (size_t)(n0 + m) * HID + k0 + 8 * c;
            *(bf16x8*)(&lB[m][c ^ (m & 7)][0]) =
                cvt8(*(const float4*)p, *(const float4*)(p + 4));
        }
        __syncthreads();
#pragma unroll
        for (int ks = 0; ks < 2; ks++) {
            bf16x8 af[2], bfr[2];
#pragma unroll
            for (int i = 0; i < 2; i++) {
                af[i]  = *(const bf16x8*)(&lA[wm + 16 * i + l16][(4 * ks + lc) ^ l7][0]);
                bfr[i] = *(const bf16x8*)(&lB[wn + 16 * i + l16][(4 * ks + lc) ^ l7][0]);
            }
#pragma unroll
            for (int i = 0; i < 2; i++)
#pragma unroll
                for (int j = 0; j < 2; j++)
                    acc[i][j] = __builtin_amdgcn_mfma_f32_16x16x32_bf16(
                        af[i], bfr[j], acc[i][j], 0, 0, 0);
        }
    }
#pragma unroll
    for (int i = 0; i < 2; i++) {
        int row = m0 + wm + 16 * i + 4 * lc;
#pragma unroll
        for (int j = 0; j < 2; j++) {
            int col = n0 + wn + 16 * j + l16;
#pragma unroll
            for (int r = 0; r < 4; r++)
                Y[(size_t)(row + r) * HID + col] = acc[i][j][r];
        }
    }
}

// ---------------- Causal attention: 4-wave LDS-shared blocks, key-split x2 ----
__global__ __launch_bounds__(256) void attn_part(
    const bf16* __restrict__ Qh, const bf16* __restrict__ Kh,
    const bf16* __restrict__ Vt, float* __restrict__ Opart,
    float* __restrict__ Lpart)
{
    const int h = blockIdx.x >> 1;
    const int ch = blockIdx.x & 1;
    const int bt = 63 - (int)blockIdx.y;     // longest-first (LPT)
    const int qb = bt * 64;
    const int nkt = bt + 1;
    const int kmid = nkt >> 1;
    const int k0 = ch ? kmid : 0;
    const int k1 = ch ? nkt : kmid;
    const int tid = threadIdx.x;
    const int lane = tid & 63, w = tid >> 6;
    const int l16 = lane & 15, lc = lane >> 4, l7 = lane & 7;

    float* Op = Opart + ((size_t)(h * 64 + bt) * 2 + ch) * 4096;
    float* Lp = Lpart + ((size_t)(h * 64 + bt) * 2 + ch) * 64;

    if (k0 >= k1) {                          // empty chunk (bt=0, ch=0)
        const f32x4 z = {0.f, 0.f, 0.f, 0.f};
#pragma unroll
        for (int i = 0; i < 4; i++)
            *(f32x4*)(Op + 4 * (tid + 256 * i)) = z;
        if (tid < 64) Lp[tid] = 0.f;
        return;
    }

    __shared__ bf16 lK[2][64][8][8];
    __shared__ bf16 lV[2][64][8][8];
    __shared__ bf16 lPT[4][16][76];

    const bf16* Kb_ = Kh + (size_t)h * S_LEN * HD;
    const bf16* Vb_ = Vt + (size_t)h * HD * S_LEN;

    int srow[2], scol[2];
#pragma unroll
    for (int i = 0; i < 2; i++) {
        int uu = tid + 256 * i;
        srow[i] = uu >> 3;
        scol[i] = uu & 7;
    }

    bf16x8 qf[2];
    {
        const bf16* qrow = Qh + (size_t)h * S_LEN * HD + (size_t)(qb + 16 * w + l16) * HD;
        qf[0] = *(const bf16x8*)(qrow + 8 * lc);
        qf[1] = *(const bf16x8*)(qrow + 32 + 8 * lc);
    }
    f32x4 oacc[4] = {};
    float l_sum = 0.f;

    // prologue: stage tile k0 into buf 0
    {
        bf16x8 kr[2], vr[2];
#pragma unroll
        for (int i = 0; i < 2; i++) {
            kr[i] = *(const bf16x8*)(Kb_ + (size_t)(k0 * 64 + srow[i]) * HD + 8 * scol[i]);
            vr[i] = *(const bf16x8*)(Vb_ + (size_t)srow[i] * S_LEN + k0 * 64 + 8 * scol[i]);
        }
#pragma unroll
        for (int i = 0; i < 2; i++) {
            *(bf16x8*)(&lK[0][srow[i]][scol[i] ^ (srow[i] & 7)][0]) = kr[i];
            *(bf16x8*)(&lV[0][srow[i]][scol[i] ^ (srow[i] & 7)][0]) = vr[i];
        }
    }

    int cur = 0;
    for (int kt = k0; kt < k1; kt++) {
        __syncthreads();

        bf16x8 kr[2], vr[2];
        if (kt + 1 < k1) {
#pragma unroll
            for (int i = 0; i < 2; i++) {
                kr[i] = *(const bf16x8*)(Kb_ + (size_t)((kt + 1) * 64 + srow[i]) * HD +
                                         8 * scol[i]);
                vr[i] = *(const bf16x8*)(Vb_ + (size_t)srow[i] * S_LEN +
                                         (kt + 1) * 64 + 8 * scol[i]);
            }
        }

        // S^T = K Q^T
        f32x4 sacc[4] = {};
#pragma unroll
        for (int ks = 0; ks < 2; ks++)
#pragma unroll
            for (int j = 0; j < 4; j++) {
                bf16x8 kf = *(const bf16x8*)(&lK[cur][16 * j + l16][(4 * ks + lc) ^ l7][0]);
                sacc[j] = __builtin_amdgcn_mfma_f32_16x16x32_bf16(
                    kf, qf[ks], sacc[j], 0, 0, 0);
            }

        float pv[4][4];
#pragma unroll
        for (int j = 0; j < 4; j++)
#pragma unroll
            for (int r = 0; r < 4; r++)
                pv[j][r] = __builtin_amdgcn_exp2f(sacc[j][r] * SCALE_LOG2E);
        if (kt == nkt - 1) {                 // diagonal tile (always in last chunk)
            const int qg = qb + 16 * w + l16;
#pragma unroll
            for (int j = 0; j < 4; j++)
#pragma unroll
                for (int r = 0; r < 4; r++) {
                    const int keyg = kt * 64 + 16 * j + 4 * lc + r;
                    if (keyg > qg) pv[j][r] = 0.f;
                }
        }
#pragma unroll
        for (int j = 0; j < 4; j++)
            l_sum += (pv[j][0] + pv[j][1]) + (pv[j][2] + pv[j][3]);

#pragma unroll
        for (int j = 0; j < 4; j++) {
            bf16x4 pp;
#pragma unroll
            for (int r = 0; r < 4; r++) pp[r] = (bf16)pv[j][r];
            *(bf16x4*)(&lPT[w][l16][16 * j + 4 * lc]) = pp;
        }
        bf16x8 pb[2];
#pragma unroll
        for (int ks = 0; ks < 2; ks++)
            pb[ks] = *(const bf16x8*)(&lPT[w][l16][32 * ks + 8 * lc]);

        // O^T += V^T P^T
#pragma unroll
        for (int ks = 0; ks < 2; ks++)
#pragma unroll
            for (int j = 0; j < 4; j++) {
                bf16x8 vf = *(const bf16x8*)(&lV[cur][16 * j + l16][(4 * ks + lc) ^ l7][0]);
                oacc[j] = __builtin_amdgcn_mfma_f32_16x16x32_bf16(
                    vf, pb[ks], oacc[j], 0, 0, 0);
            }

        if (kt + 1 < k1) {
#pragma unroll
            for (int i = 0; i < 2; i++) {
                *(bf16x8*)(&lK[cur ^ 1][srow[i]][scol[i] ^ (srow[i] & 7)][0]) = kr[i];
                *(bf16x8*)(&lV[cur ^ 1][srow[i]][scol[i] ^ (srow[i] & 7)][0]) = vr[i];
            }
        }
        cur ^= 1;
    }

    // l: combine 4 lc-replicas of each q
    l_sum += __shfl_xor(l_sum, 16, 64);
    l_sum += __shfl_xor(l_sum, 32, 64);
    if (lane < 16) Lp[16 * w + l16] = l_sum;

    // unnormalized O^T partial: Op[q*64+d]
#pragma unroll
    for (int j = 0; j < 4; j++)
        *(f32x4*)(Op + (size_t)(16 * w + l16) * 64 + 16 * j + 4 * lc) = oacc[j];
}

// combine: O = (O0+O1)/(l0+l1) -> bf16 Ob[s][h*64+d]
__global__ __launch_bounds__(256) void attn_combine(
    const float* __restrict__ Opart, const float* __restrict__ Lpart,
    bf16* __restrict__ Ob)
{
    const int h = blockIdx.x, bt = blockIdx.y;
    const size_t base = (size_t)(h * 64 + bt) * 2;
    const float* O0 = Opart + base * 4096;
    const float* O1 = O0 + 4096;
    const float* L0 = Lpart + base * 64;
    const int t = threadIdx.x;
    const int q = t >> 2, dq = (t & 3) * 16;
    const float l = L0[q] + L0[64 + q];
    const float inv = 1.0f / l;
    bf16* out = Ob + (size_t)(bt * 64 + q) * HID + h * HD + dq;
#pragma unroll
    for (int g = 0; g < 2; g++) {
        bf16x8 o8;
#pragma unroll
        for (int e = 0; e < 2; e++) {
            f32x4 a = *(const f32x4*)(O0 + q * 64 + dq + 8 * g + 4 * e);
            f32x4 b = *(const f32x4*)(O1 + q * 64 + dq + 8 * g + 4 * e);
#pragma unroll
            for (int r = 0; r < 4; r++) o8[4 * e + r] = (bf16)((a[r] + b[r]) * inv);
        }
        *(bf16x8*)(out + 8 * g) = o8;
    }
}

// ---------------- launch ----------------
extern "C" void kernel_launch(void* const* d_in, const int* in_sizes, int n_in,
                              void* d_out, int out_size, void* d_ws, size_t ws_size,
                              hipStream_t stream) {
    const float* hs   = (const float*)d_in[0];
    const float* Wq   = (const float*)d_in[1];
    const float* Wk   = (const float*)d_in[2];
    const float* Wv   = (const float*)d_in[3];
    const float* Wo   = (const float*)d_in[4];
    const float* cosT = (const float*)d_in[5];
    const float* sinT = (const float*)d_in[6];
    const int*   nreg = (const int*)d_in[7];

    char* ws = (char*)d_ws;
    const size_t MiB = 1 << 20;
    bf16*  Qh    = (bf16*)(ws);                         // 0-4   [8][S][64]
    bf16*  Kh    = (bf16*)(ws + 4 * MiB);               // 4-8   [8][S][64]
    bf16*  Vt    = (bf16*)(ws + 8 * MiB);               // 8-12  [8][64][S]
    bf16*  Ob    = (bf16*)(ws + 12 * MiB);              // 12-16 [S][512]
    float* Opart = (float*)(ws + 16 * MiB);             // 16-32 (1024 x 16KB)
    float* Lpart = (float*)(ws + 32 * MiB);             // 32-32.25

    gemm_qkv<<<dim3(4, 64, 3), 256, 0, stream>>>(hs, Wq, Wk, Wv,
                                                 cosT, sinT, nreg, Qh, Kh, Vt);
    attn_part<<<dim3(16, 64), 256, 0, stream>>>(Qh, Kh, Vt, Opart, Lpart);
    attn_combine<<<dim3(8, 64), 256, 0, stream>>>(Opart, Lpart, Ob);
    gemm_out<<<dim3(8, 64), 256, 0, stream>>>(Ob, Wo, (float*)d_out);
}